// Round 4
// baseline (1339.582 us; speedup 1.0000x reference)
//
#include <hip/hip_runtime.h>
#include <math.h>

#define BB   32
#define DD   128
#define HH   64
#define WW   64
#define KK   1024
#define HWW  (HH * WW)      // 4096
#define NPIX (BB * HWW)     // 131072
#define EPS  1e-4f          // covers exact-formula ulp(~128) wobble + screen error
#define HARD_CAP 65536

// ws layout in float slots:
#define WS_WT    0           // fp32 wT[K][D]                131072
#define WS_E2    131072      // fp32 e2[K]                     1024
#define WS_CTR   132096      // int counter (pad to 64)
#define WS_LIST  132160      // int hard_list[HARD_CAP]       65536
#define WS_BEST  197696      // u64 hard_best[HARD_CAP]      131072 slots (8B-aligned)
#define WS_BHI   328768      // bf16 B-frags hi               65536
#define WS_BLO   394304      // bf16 B-frags lo               65536  -> 1.76 MB total

typedef short  short8  __attribute__((ext_vector_type(8)));
typedef float  floatx4 __attribute__((ext_vector_type(4)));

static __device__ __forceinline__ unsigned short f2bf(float x) {
    unsigned u = __float_as_uint(x);
    unsigned r = (u + 0x7fffu + ((u >> 16) & 1u)) >> 16;
    return (unsigned short)r;
}
static __device__ __forceinline__ float bf2f(unsigned short b) {
    return __uint_as_float(((unsigned)b) << 16);
}

// ---------------------------------------------------------------------------
// Prep 1: transpose w[D][K] -> wT[K][D] fp32.
// ---------------------------------------------------------------------------
__global__ void prep_wt(const float* __restrict__ w, float* __restrict__ wT) {
    int t  = blockIdx.x * 256 + threadIdx.x;   // 0..32767
    int k  = t & 1023;
    int d4 = t >> 10;
    float4 v;
    v.x = w[(d4 * 4 + 0) * KK + k];
    v.y = w[(d4 * 4 + 1) * KK + k];
    v.z = w[(d4 * 4 + 2) * KK + k];
    v.w = w[(d4 * 4 + 3) * KK + k];
    *(float4*)(wT + (size_t)k * DD + d4 * 4) = v;
}

// ---------------------------------------------------------------------------
// Prep 2: bf16 hi/lo B-fragments in MFMA B-operand layout (verified r3).
// unit u = (ktile*4 + chunk)*64 + lane : B[kdim=chunk*32+(lane>>4)*8+j][n=ktile*16+(lane&15)]
// ---------------------------------------------------------------------------
__global__ void prep_bfrag(const float* __restrict__ w,
                           short8* __restrict__ bhi, short8* __restrict__ blo) {
    int t     = blockIdx.x * 256 + threadIdx.x;  // 0..16383
    int lane  = t & 63;
    int chunk = (t >> 6) & 3;
    int ktile = t >> 8;
    int kcol  = ktile * 16 + (lane & 15);
    int d0    = chunk * 32 + (lane >> 4) * 8;
    short8 h, l;
#pragma unroll
    for (int j = 0; j < 8; ++j) {
        float wv = w[(size_t)(d0 + j) * KK + kcol];
        unsigned short hb = f2bf(wv);
        h[j] = (short)hb;
        l[j] = (short)f2bf(wv - bf2f(hb));
    }
    bhi[t] = h;
    blo[t] = l;
}

// ---------------------------------------------------------------------------
// Prep 3: e2[k] numpy-order; zero hard counter.
// ---------------------------------------------------------------------------
__global__ void prep_e2(const float* __restrict__ wT, float* __restrict__ e2,
                        int* __restrict__ ctr) {
    int k = blockIdx.x * 256 + threadIdx.x;
    if (k == 0) ctr[0] = 0;
    if (k >= KK) return;
    const float* row = wT + (size_t)k * DD;
    float acc = 0.0f;
    for (int d = 0; d < DD; ++d) acc = __fadd_rn(acc, __fmul_rn(row[d], row[d]));
    e2[k] = acc;
}

// ---------------------------------------------------------------------------
// Screen: block = 4 waves x 16 pixels. Fragments staged through LDS once per
// block (register-prefetch double-buffer, 1 barrier/iter) -> 4x less L2
// traffic vs r3. MFMA + top-2 arithmetic identical to the passing r3 kernel.
// ---------------------------------------------------------------------------
__global__ __launch_bounds__(256) void vq_screen(
        const float* __restrict__ x,
        const float* __restrict__ wT,
        const float* __restrict__ e2,
        const short8* __restrict__ bhi,
        const short8* __restrict__ blo,
        float* __restrict__ out,
        int* __restrict__ hard_list,
        unsigned long long* __restrict__ hard_best,
        int* __restrict__ hard_ctr) {
    __shared__ short8 ls_hi[2][256];   // 8 KB
    __shared__ short8 ls_lo[2][256];   // 8 KB
    __shared__ int sk1[4][16];

    const int tid  = threadIdx.x;
    const int wave = tid >> 6;
    const int lane = tid & 63;
    const int q    = lane >> 4;
    const int col  = lane & 15;

    const int b        = blockIdx.x >> 6;
    const int wbase_hw = (blockIdx.x & 63) * 64 + wave * 16;
    const int hw       = wbase_hw + col;

    // A fragments: x[pixel=col][d = chunk*32 + q*8 + j], bf16 hi/lo split
    short8 ahi[4], alo[4];
#pragma unroll
    for (int chunk = 0; chunk < 4; ++chunk) {
#pragma unroll
        for (int j = 0; j < 8; ++j) {
            int d = chunk * 32 + q * 8 + j;
            float xf = x[(size_t)(b * DD + d) * HWW + hw];
            unsigned short hb = f2bf(xf);
            ahi[chunk][j] = (short)hb;
            alo[chunk][j] = (short)f2bf(xf - bf2f(hb));
        }
    }

    float b1[4] = {INFINITY, INFINITY, INFINITY, INFINITY};
    float b2[4] = {INFINITY, INFINITY, INFINITY, INFINITY};
    int   k1[4] = {0, 0, 0, 0};

    // prefetch tile 0
    short8 ph = bhi[tid];
    short8 pl = blo[tid];

    for (int kt = 0; kt < KK / 16; ++kt) {
        const int cur = kt & 1;
        ls_hi[cur][tid] = ph;
        ls_lo[cur][tid] = pl;
        if (kt < KK / 16 - 1) {
            ph = bhi[(kt + 1) * 256 + tid];
            pl = blo[(kt + 1) * 256 + tid];
        }
        __syncthreads();

        short8 bh0 = ls_hi[cur][0 * 64 + lane];
        short8 bh1 = ls_hi[cur][1 * 64 + lane];
        short8 bh2 = ls_hi[cur][2 * 64 + lane];
        short8 bh3 = ls_hi[cur][3 * 64 + lane];
        short8 bl0 = ls_lo[cur][0 * 64 + lane];
        short8 bl1 = ls_lo[cur][1 * 64 + lane];
        short8 bl2 = ls_lo[cur][2 * 64 + lane];
        short8 bl3 = ls_lo[cur][3 * 64 + lane];
        float e2v = e2[kt * 16 + col];

        floatx4 accA = {0.f, 0.f, 0.f, 0.f};
        floatx4 accB = {0.f, 0.f, 0.f, 0.f};
        accA = __builtin_amdgcn_mfma_f32_16x16x32_bf16(ahi[0], bh0, accA, 0, 0, 0);
        accB = __builtin_amdgcn_mfma_f32_16x16x32_bf16(ahi[1], bh1, accB, 0, 0, 0);
        accA = __builtin_amdgcn_mfma_f32_16x16x32_bf16(ahi[2], bh2, accA, 0, 0, 0);
        accB = __builtin_amdgcn_mfma_f32_16x16x32_bf16(ahi[3], bh3, accB, 0, 0, 0);
        accA = __builtin_amdgcn_mfma_f32_16x16x32_bf16(ahi[0], bl0, accA, 0, 0, 0);
        accB = __builtin_amdgcn_mfma_f32_16x16x32_bf16(ahi[1], bl1, accB, 0, 0, 0);
        accA = __builtin_amdgcn_mfma_f32_16x16x32_bf16(ahi[2], bl2, accA, 0, 0, 0);
        accB = __builtin_amdgcn_mfma_f32_16x16x32_bf16(ahi[3], bl3, accB, 0, 0, 0);
        accA = __builtin_amdgcn_mfma_f32_16x16x32_bf16(alo[0], bh0, accA, 0, 0, 0);
        accB = __builtin_amdgcn_mfma_f32_16x16x32_bf16(alo[1], bh1, accB, 0, 0, 0);
        accA = __builtin_amdgcn_mfma_f32_16x16x32_bf16(alo[2], bh2, accA, 0, 0, 0);
        accB = __builtin_amdgcn_mfma_f32_16x16x32_bf16(alo[3], bh3, accB, 0, 0, 0);

        const int kcur = kt * 16 + col;
#pragma unroll
        for (int r = 0; r < 4; ++r) {
            float s = fmaf(-2.0f, accA[r] + accB[r], e2v);
            bool lt = s < b1[r];
            b2[r] = fminf(fmaxf(s, b1[r]), b2[r]);   // exact 2nd-smallest recurrence
            k1[r] = lt ? kcur : k1[r];
            b1[r] = fminf(s, b1[r]);
        }
    }

    // Butterfly merge across the 16 columns.
#pragma unroll
    for (int off = 1; off < 16; off <<= 1) {
#pragma unroll
        for (int r = 0; r < 4; ++r) {
            float ob1 = __shfl_xor(b1[r], off);
            float ob2 = __shfl_xor(b2[r], off);
            int   ok1 = __shfl_xor(k1[r], off);
            float nb2 = fminf(fmaxf(b1[r], ob1), fminf(b2[r], ob2));
            bool take = (ob1 < b1[r]) || (ob1 == b1[r] && ok1 < k1[r]);
            b1[r] = take ? ob1 : b1[r];
            k1[r] = take ? ok1 : k1[r];
            b2[r] = nb2;
        }
    }

#pragma unroll
    for (int r = 0; r < 4; ++r) {
        if (col == r) {
            int plocal = q * 4 + r;
            int hwp    = wbase_hw + plocal;
            int Pg     = b * HWW + hwp;
            out[(size_t)DD * NPIX + Pg] = (float)k1[r];
            sk1[wave][plocal] = k1[r];
            if (b2[r] - b1[r] <= EPS) {
                int idx = atomicAdd(hard_ctr, 1);
                if (idx < HARD_CAP) {
                    hard_list[idx] = Pg;
                    hard_best[idx] = ~0ull;
                }
            }
        }
    }
    __syncthreads();

    // Gather epilogue (verified r3)
    {
        const int plocal = lane & 15;
        const int dgrp   = lane >> 4;
        const int kk     = sk1[wave][plocal];
        const int hwp    = wbase_hw + plocal;
        const float* wrow = wT + (size_t)kk * DD;
#pragma unroll
        for (int i = 0; i < 32; ++i) {
            int d = i * 4 + dgrp;
            out[(size_t)(b * DD + d) * HWW + hwp] = wrow[d];
        }
    }
}

// ---------------------------------------------------------------------------
// Exact pass: task = (16-pixel batch) x (k-quarter of 256 rows). Codebook
// quarter streamed through LDS in 64-row tiles (pad 132: conflict-free, 16B
// aligned); x staged in LDS. Byte-exact numpy-order arithmetic per (p,k).
// Per-pixel lexicographic (d2bits,k) min -> atomicMin u64 (ties -> min k ==
// numpy first occurrence; d2 > 0 so float bit order == value order).
// ---------------------------------------------------------------------------
#define XPAD 132
__global__ __launch_bounds__(256) void vq_exact(
        const float* __restrict__ x,
        const float* __restrict__ wT,
        const float* __restrict__ e2,
        const int* __restrict__ hard_list,
        const int* __restrict__ hard_ctr,
        unsigned long long* __restrict__ hard_best) {
    __shared__ float sw[64 * XPAD];                  // 33.8 KB
    __shared__ float sx[16 * XPAD];                  // 8.45 KB
    __shared__ unsigned long long red[16][17];       // 2.1 KB

    const int tid   = threadIdx.x;
    const int p_l   = tid & 15;
    const int slice = tid >> 4;                      // 0..15

    const int count = min(hard_ctr[0], HARD_CAP);
    const int ntask = ((count + 15) >> 4) * 4;

    for (int task = blockIdx.x; task < ntask; task += gridDim.x) {
        const int batch   = task >> 2;
        const int quarter = task & 3;
        const int base    = batch * 16;
        const int nb      = min(16, count - base);

        __syncthreads();   // previous task's LDS readers done
        for (int i = tid; i < 16 * DD; i += 256) {
            int pp = i >> 7, d = i & 127;
            int pg = hard_list[base + (pp < nb ? pp : 0)];
            sx[pp * XPAD + d] =
                x[(size_t)((pg >> 12) * DD + d) * HWW + (pg & (HWW - 1))];
        }
        __syncthreads();

        const float* xr = sx + p_l * XPAD;
        float x2 = 0.0f;
        for (int d = 0; d < DD; ++d) x2 = __fadd_rn(x2, __fmul_rn(xr[d], xr[d]));

        unsigned long long mybest = ~0ull;
        for (int tile = 0; tile < 4; ++tile) {
            const int k0 = quarter * 256 + tile * 64;
            __syncthreads();   // previous tile fully consumed
            for (int i = tid; i < 64 * 32; i += 256) {
                int row = i >> 5, c4 = i & 31;
                *(float4*)(sw + row * XPAD + c4 * 4) =
                    *(const float4*)(wT + (size_t)(k0 + row) * DD + c4 * 4);
            }
            __syncthreads();

            // two independent chains (rows kl and kl+2) for ILP
#pragma unroll
            for (int kk = 0; kk < 2; ++kk) {
                const int kl0 = slice * 4 + kk;
                const int kl1 = kl0 + 2;
                const float* w0 = sw + kl0 * XPAD;
                const float* w1 = sw + kl1 * XPAD;
                float a0 = 0.0f, a1 = 0.0f;
                for (int d4 = 0; d4 < 32; ++d4) {
                    float4 xv = *(const float4*)(xr + 4 * d4);
                    float4 v0 = *(const float4*)(w0 + 4 * d4);
                    float4 v1 = *(const float4*)(w1 + 4 * d4);
                    a0 = __fadd_rn(a0, __fmul_rn(xv.x, v0.x));
                    a1 = __fadd_rn(a1, __fmul_rn(xv.x, v1.x));
                    a0 = __fadd_rn(a0, __fmul_rn(xv.y, v0.y));
                    a1 = __fadd_rn(a1, __fmul_rn(xv.y, v1.y));
                    a0 = __fadd_rn(a0, __fmul_rn(xv.z, v0.z));
                    a1 = __fadd_rn(a1, __fmul_rn(xv.z, v1.z));
                    a0 = __fadd_rn(a0, __fmul_rn(xv.w, v0.w));
                    a1 = __fadd_rn(a1, __fmul_rn(xv.w, v1.w));
                }
                int k_0 = k0 + kl0, k_1 = k0 + kl1;
                float d20 = __fadd_rn(__fsub_rn(x2, 2.0f * a0), e2[k_0]);
                float d21 = __fadd_rn(__fsub_rn(x2, 2.0f * a1), e2[k_1]);
                unsigned long long c0 =
                    ((unsigned long long)__float_as_uint(d20) << 32) | (unsigned)k_0;
                unsigned long long c1 =
                    ((unsigned long long)__float_as_uint(d21) << 32) | (unsigned)k_1;
                mybest = mybest < c0 ? mybest : c0;
                mybest = mybest < c1 ? mybest : c1;
            }
        }

        red[slice][p_l] = mybest;
        __syncthreads();
        if (slice == 0 && p_l < nb) {
            unsigned long long m = red[0][p_l];
#pragma unroll
            for (int s = 1; s < 16; ++s) m = min(m, red[s][p_l]);
            atomicMin(&hard_best[base + p_l], m);
        }
    }
}

// ---------------------------------------------------------------------------
// Finish: overwrite argmin + gathered row for hard pixels. One wave/pixel.
// ---------------------------------------------------------------------------
__global__ __launch_bounds__(256) void vq_finish(
        const float* __restrict__ wT,
        float* __restrict__ out,
        const int* __restrict__ hard_list,
        const int* __restrict__ hard_ctr,
        const unsigned long long* __restrict__ hard_best) {
    const int count = min(hard_ctr[0], HARD_CAP);
    const int wave  = (blockIdx.x * 256 + threadIdx.x) >> 6;
    const int lane  = threadIdx.x & 63;
    for (int j = wave; j < count; j += 1024) {
        const int p     = hard_list[j];
        const int bestk = (int)(hard_best[j] & 0xffffffffu);
        const int b  = p >> 12;
        const int hw = p & (HWW - 1);
        if (lane == 0) out[(size_t)DD * NPIX + p] = (float)bestk;
        const float* wb = wT + (size_t)bestk * DD;
        float* op = out + (size_t)b * DD * HWW + hw;
        op[(size_t)lane * HWW]        = wb[lane];
        op[(size_t)(lane + 64) * HWW] = wb[lane + 64];
    }
}

extern "C" void kernel_launch(void* const* d_in, const int* in_sizes, int n_in,
                              void* d_out, int out_size, void* d_ws, size_t ws_size,
                              hipStream_t stream) {
    const float* x = (const float*)d_in[0];
    const float* w = (const float*)d_in[1];
    float* out = (float*)d_out;
    float* wsf = (float*)d_ws;

    float*  wT   = wsf + WS_WT;
    float*  e2   = wsf + WS_E2;
    int*    ctr  = (int*)(wsf + WS_CTR);
    int*    list = (int*)(wsf + WS_LIST);
    unsigned long long* best = (unsigned long long*)(wsf + WS_BEST);
    short8* bhi  = (short8*)(wsf + WS_BHI);
    short8* blo  = (short8*)(wsf + WS_BLO);

    prep_wt   <<<dim3(128),  dim3(256), 0, stream>>>(w, wT);
    prep_bfrag<<<dim3(64),   dim3(256), 0, stream>>>(w, bhi, blo);
    prep_e2   <<<dim3(4),    dim3(256), 0, stream>>>(wT, e2, ctr);
    vq_screen <<<dim3(2048), dim3(256), 0, stream>>>(x, wT, e2, bhi, blo, out,
                                                     list, best, ctr);
    vq_exact  <<<dim3(1024), dim3(256), 0, stream>>>(x, wT, e2, list, ctr, best);
    vq_finish <<<dim3(256),  dim3(256), 0, stream>>>(wT, out, list, ctr, best);
}

// Round 5
// 519.057 us; speedup vs baseline: 2.5808x; 2.5808x over previous
//
#include <hip/hip_runtime.h>
#include <math.h>

#define BB   32
#define DD   128
#define HH   64
#define WW   64
#define KK   1024
#define HWW  (HH * WW)      // 4096
#define NPIX (BB * HWW)     // 131072
#define EPS  1.5e-4f        // >= 3.5x the 4.2e-5 worst-case pair-comparison bound
#define CAPA 32768
#define CAPB 8192

// ws layout in float slots:
#define WS_WT    0           // fp32 wT[K][D]            131072
#define WS_E2    131072      // fp32 e2[K]                 1024
#define WS_CTR   132096      // int ctrA, ctrB (pad 64)
#define WS_LISTA 132160      // int {p,k1,k2} x CAPA      98304
#define WS_LISTB 230464      // int {p,win}  x CAPB       16384
#define WS_BHI   246848      // bf16 B-frags hi           65536
#define WS_BLO   312384      // bf16 B-frags lo           65536   -> 1.51 MB

typedef short  short8  __attribute__((ext_vector_type(8)));
typedef float  floatx4 __attribute__((ext_vector_type(4)));

static __device__ __forceinline__ unsigned short f2bf(float x) {
    unsigned u = __float_as_uint(x);
    unsigned r = (u + 0x7fffu + ((u >> 16) & 1u)) >> 16;
    return (unsigned short)r;
}
static __device__ __forceinline__ float bf2f(unsigned short b) {
    return __uint_as_float(((unsigned)b) << 16);
}

// ---------------------------------------------------------------------------
// Prep 1: transpose w[D][K] -> wT[K][D] fp32.
// ---------------------------------------------------------------------------
__global__ void prep_wt(const float* __restrict__ w, float* __restrict__ wT) {
    int t  = blockIdx.x * 256 + threadIdx.x;   // 0..32767
    int k  = t & 1023;
    int d4 = t >> 10;
    float4 v;
    v.x = w[(d4 * 4 + 0) * KK + k];
    v.y = w[(d4 * 4 + 1) * KK + k];
    v.z = w[(d4 * 4 + 2) * KK + k];
    v.w = w[(d4 * 4 + 3) * KK + k];
    *(float4*)(wT + (size_t)k * DD + d4 * 4) = v;
}

// ---------------------------------------------------------------------------
// Prep 2: bf16 hi/lo B-fragments in MFMA B-operand layout (verified r3/r4).
// unit t = ktile*256 + chunk*64 + lane :
//   B[kdim=chunk*32+(lane>>4)*8+j][n=ktile*16+(lane&15)], j=0..7
// ---------------------------------------------------------------------------
__global__ void prep_bfrag(const float* __restrict__ w,
                           short8* __restrict__ bhi, short8* __restrict__ blo) {
    int t     = blockIdx.x * 256 + threadIdx.x;  // 0..16383
    int lane  = t & 63;
    int chunk = (t >> 6) & 3;
    int ktile = t >> 8;
    int kcol  = ktile * 16 + (lane & 15);
    int d0    = chunk * 32 + (lane >> 4) * 8;
    short8 h, l;
#pragma unroll
    for (int j = 0; j < 8; ++j) {
        float wv = w[(size_t)(d0 + j) * KK + kcol];
        unsigned short hb = f2bf(wv);
        h[j] = (short)hb;
        l[j] = (short)f2bf(wv - bf2f(hb));
    }
    bhi[t] = h;
    blo[t] = l;
}

// ---------------------------------------------------------------------------
// Prep 3: e2[k] numpy-order (sequential d, separate mul/add); zero counters.
// ---------------------------------------------------------------------------
__global__ void prep_e2(const float* __restrict__ wT, float* __restrict__ e2,
                        int* __restrict__ ctr) {
    int k = blockIdx.x * 256 + threadIdx.x;
    if (k == 0) { ctr[0] = 0; ctr[1] = 0; }
    if (k >= KK) return;
    const float* row = wT + (size_t)k * DD;
    float acc = 0.0f;
    for (int d = 0; d < DD; ++d) acc = __fadd_rn(acc, __fmul_rn(row[d], row[d]));
    e2[k] = acc;
}

// ---------------------------------------------------------------------------
// Screen: wave = 32 pixels (2 A-groups) x all 1024 k via split-bf16 MFMA.
// No LDS staging, no barriers in the K-loop: fragments stream L2->registers
// and each wave pipelines loads under MFMAs freely. Tracks top-3 screen
// scores (s1,k1),(s2,k2),s3 per pixel. Classification:
//   s2-s1 >  EPS : winner = k1 (proven)
//   s3-s1 >  EPS : 2-candidate pixel -> listA {p,k1,k2}
//   else         : full-scan pixel   -> listB {p}
// ---------------------------------------------------------------------------
__global__ __launch_bounds__(256) void vq_screen(
        const float* __restrict__ x,
        const float* __restrict__ wT,
        const float* __restrict__ e2,
        const short8* __restrict__ bhi,
        const short8* __restrict__ blo,
        float* __restrict__ out,
        int* __restrict__ listA,
        int* __restrict__ listB,
        int* __restrict__ ctr) {
    __shared__ int sk1[4][32];

    const int tid  = threadIdx.x;
    const int wave = tid >> 6;
    const int lane = tid & 63;
    const int q    = lane >> 4;
    const int col  = lane & 15;

    const int b       = blockIdx.x >> 5;                    // 32 blocks/image
    const int base_hw = (blockIdx.x & 31) * 128 + wave * 32;

    // A fragments for both pixel groups: x[pixel][d = chunk*32 + q*8 + j]
    short8 a0h[4], a0l[4], a1h[4], a1l[4];
#pragma unroll
    for (int c = 0; c < 4; ++c) {
#pragma unroll
        for (int j = 0; j < 8; ++j) {
            int d = c * 32 + q * 8 + j;
            const float* xr = x + (size_t)(b * DD + d) * HWW + base_hw;
            float x0 = xr[col];
            float x1 = xr[16 + col];
            unsigned short h0 = f2bf(x0), h1 = f2bf(x1);
            a0h[c][j] = (short)h0;  a0l[c][j] = (short)f2bf(x0 - bf2f(h0));
            a1h[c][j] = (short)h1;  a1l[c][j] = (short)f2bf(x1 - bf2f(h1));
        }
    }

    float s1[8], s2[8], s3[8];
    int   c1[8], c2[8];
#pragma unroll
    for (int i = 0; i < 8; ++i) {
        s1[i] = INFINITY; s2[i] = INFINITY; s3[i] = INFINITY;
        c1[i] = 0; c2[i] = 0;
    }

    for (int kt = 0; kt < KK / 16; ++kt) {
        const int ub = kt * 256 + lane;
        short8 bh0 = bhi[ub + 0 * 64], bh1 = bhi[ub + 1 * 64];
        short8 bh2 = bhi[ub + 2 * 64], bh3 = bhi[ub + 3 * 64];
        short8 bl0 = blo[ub + 0 * 64], bl1 = blo[ub + 1 * 64];
        short8 bl2 = blo[ub + 2 * 64], bl3 = blo[ub + 3 * 64];
        float e2v = e2[kt * 16 + col];

        floatx4 p00 = {0.f,0.f,0.f,0.f}, p01 = {0.f,0.f,0.f,0.f};
        floatx4 p10 = {0.f,0.f,0.f,0.f}, p11 = {0.f,0.f,0.f,0.f};
        // group 0: hi*hi, hi*lo, lo*hi   (verified split arithmetic)
        p00 = __builtin_amdgcn_mfma_f32_16x16x32_bf16(a0h[0], bh0, p00, 0,0,0);
        p01 = __builtin_amdgcn_mfma_f32_16x16x32_bf16(a0h[1], bh1, p01, 0,0,0);
        p00 = __builtin_amdgcn_mfma_f32_16x16x32_bf16(a0h[2], bh2, p00, 0,0,0);
        p01 = __builtin_amdgcn_mfma_f32_16x16x32_bf16(a0h[3], bh3, p01, 0,0,0);
        p00 = __builtin_amdgcn_mfma_f32_16x16x32_bf16(a0h[0], bl0, p00, 0,0,0);
        p01 = __builtin_amdgcn_mfma_f32_16x16x32_bf16(a0h[1], bl1, p01, 0,0,0);
        p00 = __builtin_amdgcn_mfma_f32_16x16x32_bf16(a0h[2], bl2, p00, 0,0,0);
        p01 = __builtin_amdgcn_mfma_f32_16x16x32_bf16(a0h[3], bl3, p01, 0,0,0);
        p00 = __builtin_amdgcn_mfma_f32_16x16x32_bf16(a0l[0], bh0, p00, 0,0,0);
        p01 = __builtin_amdgcn_mfma_f32_16x16x32_bf16(a0l[1], bh1, p01, 0,0,0);
        p00 = __builtin_amdgcn_mfma_f32_16x16x32_bf16(a0l[2], bh2, p00, 0,0,0);
        p01 = __builtin_amdgcn_mfma_f32_16x16x32_bf16(a0l[3], bh3, p01, 0,0,0);
        // group 1
        p10 = __builtin_amdgcn_mfma_f32_16x16x32_bf16(a1h[0], bh0, p10, 0,0,0);
        p11 = __builtin_amdgcn_mfma_f32_16x16x32_bf16(a1h[1], bh1, p11, 0,0,0);
        p10 = __builtin_amdgcn_mfma_f32_16x16x32_bf16(a1h[2], bh2, p10, 0,0,0);
        p11 = __builtin_amdgcn_mfma_f32_16x16x32_bf16(a1h[3], bh3, p11, 0,0,0);
        p10 = __builtin_amdgcn_mfma_f32_16x16x32_bf16(a1h[0], bl0, p10, 0,0,0);
        p11 = __builtin_amdgcn_mfma_f32_16x16x32_bf16(a1h[1], bl1, p11, 0,0,0);
        p10 = __builtin_amdgcn_mfma_f32_16x16x32_bf16(a1h[2], bl2, p10, 0,0,0);
        p11 = __builtin_amdgcn_mfma_f32_16x16x32_bf16(a1h[3], bl3, p11, 0,0,0);
        p10 = __builtin_amdgcn_mfma_f32_16x16x32_bf16(a1l[0], bh0, p10, 0,0,0);
        p11 = __builtin_amdgcn_mfma_f32_16x16x32_bf16(a1l[1], bh1, p11, 0,0,0);
        p10 = __builtin_amdgcn_mfma_f32_16x16x32_bf16(a1l[2], bh2, p10, 0,0,0);
        p11 = __builtin_amdgcn_mfma_f32_16x16x32_bf16(a1l[3], bh3, p11, 0,0,0);

        const int kcur = kt * 16 + col;
#pragma unroll
        for (int g = 0; g < 2; ++g) {
#pragma unroll
            for (int r = 0; r < 4; ++r) {
                const int i = g * 4 + r;
                float s = fmaf(-2.0f,
                               (g == 0 ? p00[r] + p01[r] : p10[r] + p11[r]),
                               e2v);
                bool lt1 = s < s1[i];
                bool lt2 = s < s2[i];
                bool lt3 = s < s3[i];
                s3[i] = lt2 ? s2[i] : (lt3 ? s : s3[i]);
                s2[i] = lt1 ? s1[i] : (lt2 ? s : s2[i]);
                c2[i] = lt1 ? c1[i] : (lt2 ? kcur : c2[i]);
                s1[i] = lt1 ? s : s1[i];
                c1[i] = lt1 ? kcur : c1[i];
            }
        }
    }

    // Butterfly merge of sorted top-3 states across the 16 k-columns.
#pragma unroll
    for (int off = 1; off < 16; off <<= 1) {
#pragma unroll
        for (int i = 0; i < 8; ++i) {
            float o1 = __shfl_xor(s1[i], off);
            float o2 = __shfl_xor(s2[i], off);
            float o3 = __shfl_xor(s3[i], off);
            int   ok1 = __shfl_xor(c1[i], off);
            int   ok2 = __shfl_xor(c2[i], off);
            bool afirst = (s1[i] < o1) || (s1[i] == o1 && c1[i] < ok1);
            // lex-ordered merge of two sorted triples -> new top-3
            float n1, n2, n3; int nk1, nk2;
            if (afirst) {
                bool asec = (s2[i] < o1) || (s2[i] == o1 && c2[i] < ok1);
                n1 = s1[i]; nk1 = c1[i];
                n2 = asec ? s2[i] : o1;  nk2 = asec ? c2[i] : ok1;
                n3 = asec ? fminf(s3[i], o1) : fminf(s2[i], o2);
            } else {
                bool bsec = (o2 < s1[i]) || (o2 == s1[i] && ok2 < c1[i]);
                n1 = o1; nk1 = ok1;
                n2 = bsec ? o2 : s1[i];  nk2 = bsec ? ok2 : c1[i];
                n3 = bsec ? fminf(o3, s1[i]) : fminf(o2, s2[i]);
            }
            s1[i] = n1; s2[i] = n2; s3[i] = n3; c1[i] = nk1; c2[i] = nk2;
        }
    }

    // Publish: lane q*16+r publishes pixels g*16 + q*4 + r for g=0,1.
#pragma unroll
    for (int g = 0; g < 2; ++g) {
#pragma unroll
        for (int r = 0; r < 4; ++r) {
            if (col == r) {
                const int i = g * 4 + r;
                int plocal = g * 16 + q * 4 + r;
                int hwp    = base_hw + plocal;
                int Pg     = b * HWW + hwp;
                out[(size_t)DD * NPIX + Pg] = (float)c1[i];
                sk1[wave][plocal] = c1[i];
                float g12 = s2[i] - s1[i];
                float g13 = s3[i] - s1[i];
                if (g12 <= EPS) {
                    if (g13 > EPS) {
                        int idx = atomicAdd(&ctr[0], 1);
                        if (idx < CAPA) {
                            listA[3 * idx + 0] = Pg;
                            listA[3 * idx + 1] = c1[i];
                            listA[3 * idx + 2] = c2[i];
                        }
                    } else {
                        int idx = atomicAdd(&ctr[1], 1);
                        if (idx < CAPB) listB[2 * idx] = Pg;
                    }
                }
            }
        }
    }
    __syncthreads();

    // Gather epilogue (r3/r4 pattern, two 16-pixel halves per wave).
    {
        const int p_lo = lane & 15;
        const int dgrp = lane >> 4;
#pragma unroll
        for (int half = 0; half < 2; ++half) {
            const int plocal = half * 16 + p_lo;
            const int kk     = sk1[wave][plocal];
            const int hwp    = base_hw + plocal;
            const float* wrow = wT + (size_t)kk * DD;
#pragma unroll
            for (int i = 0; i < 32; ++i) {
                int d = i * 4 + dgrp;
                out[(size_t)(b * DD + d) * HWW + hwp] = wrow[d];
            }
        }
    }
}

// ---------------------------------------------------------------------------
// Pair resolve: one thread per 2-candidate pixel. Byte-exact numpy-order
// x2, xe(kA), xe(kB) chains; winner = lex-min((d2,k)). Entries spread
// block-major so few entries still cover many CUs.
// ---------------------------------------------------------------------------
__global__ __launch_bounds__(256) void vq_pair(
        const float* __restrict__ x,
        const float* __restrict__ wT,
        const float* __restrict__ e2,
        int* __restrict__ listA,
        const int* __restrict__ ctr) {
    const int n = min(ctr[0], CAPA);
    const int NT = gridDim.x * 256;
    for (int j = blockIdx.x + threadIdx.x * gridDim.x; j < n; j += NT) {
        const int p  = listA[3 * j + 0];
        const int kA = listA[3 * j + 1];
        const int kB = listA[3 * j + 2];
        const int b  = p >> 12;
        const int hw = p & (HWW - 1);
        const float* xp = x + (size_t)b * DD * HWW + hw;
        const float* wa = wT + (size_t)kA * DD;
        const float* wb = wT + (size_t)kB * DD;
        float x2 = 0.0f, aa = 0.0f, ab = 0.0f;
#pragma unroll 4
        for (int d = 0; d < DD; ++d) {
            float xd = xp[(size_t)d * HWW];
            x2 = __fadd_rn(x2, __fmul_rn(xd, xd));
            aa = __fadd_rn(aa, __fmul_rn(xd, wa[d]));
            ab = __fadd_rn(ab, __fmul_rn(xd, wb[d]));
        }
        float dA = __fadd_rn(__fsub_rn(x2, 2.0f * aa), e2[kA]);
        float dB = __fadd_rn(__fsub_rn(x2, 2.0f * ab), e2[kB]);
        int win = (dA < dB || (dA == dB && kA < kB)) ? kA : kB;
        listA[3 * j + 1] = win;
    }
}

// ---------------------------------------------------------------------------
// Full resolve: wave per 3+-candidate pixel (rare). Lane owns 16 rows,
// exact chains, u64 (d2bits,k) lex-min butterfly (d2 > 0 always).
// ---------------------------------------------------------------------------
__global__ __launch_bounds__(256) void vq_full(
        const float* __restrict__ x,
        const float* __restrict__ wT,
        const float* __restrict__ e2,
        int* __restrict__ listB,
        const int* __restrict__ ctr) {
    const int n = min(ctr[1], CAPB);
    const int wave = (blockIdx.x * 256 + threadIdx.x) >> 6;
    const int lane = threadIdx.x & 63;
    const int NW = (gridDim.x * 256) >> 6;
    for (int j = wave; j < n; j += NW) {
        const int p  = listB[2 * j];
        const int b  = p >> 12;
        const int hw = p & (HWW - 1);
        const float* xp = x + (size_t)b * DD * HWW + hw;
        float xv[DD];
#pragma unroll 4
        for (int d = 0; d < DD; ++d) xv[d] = xp[(size_t)d * HWW];
        float x2 = 0.0f;
#pragma unroll 4
        for (int d = 0; d < DD; ++d) x2 = __fadd_rn(x2, __fmul_rn(xv[d], xv[d]));

        unsigned long long best = ~0ull;
        for (int kk = 0; kk < 16; ++kk) {
            const int k = lane * 16 + kk;
            const float* wk = wT + (size_t)k * DD;
            float a = 0.0f;
#pragma unroll 4
            for (int d = 0; d < DD; ++d)
                a = __fadd_rn(a, __fmul_rn(xv[d], wk[d]));
            float d2 = __fadd_rn(__fsub_rn(x2, 2.0f * a), e2[k]);
            unsigned long long c =
                ((unsigned long long)__float_as_uint(d2) << 32) | (unsigned)k;
            best = best < c ? best : c;
        }
#pragma unroll
        for (int off = 32; off; off >>= 1) {
            unsigned long long o = __shfl_xor(best, off);
            best = best < o ? best : o;
        }
        if (lane == 0) listB[2 * j + 1] = (int)(best & 0xffffffffu);
    }
}

// ---------------------------------------------------------------------------
// Finish: overwrite argmin + gathered row for all hard pixels. Wave/pixel.
// ---------------------------------------------------------------------------
__global__ __launch_bounds__(256) void vq_finish(
        const float* __restrict__ wT,
        float* __restrict__ out,
        const int* __restrict__ listA,
        const int* __restrict__ listB,
        const int* __restrict__ ctr) {
    const int nA = min(ctr[0], CAPA);
    const int nB = min(ctr[1], CAPB);
    const int wave = (blockIdx.x * 256 + threadIdx.x) >> 6;
    const int lane = threadIdx.x & 63;
    const int NW = (gridDim.x * 256) >> 6;
    for (int j = wave; j < nA + nB; j += NW) {
        int p, kwin;
        if (j < nA) { p = listA[3 * j]; kwin = listA[3 * j + 1]; }
        else        { p = listB[2 * (j - nA)]; kwin = listB[2 * (j - nA) + 1]; }
        const int b  = p >> 12;
        const int hw = p & (HWW - 1);
        if (lane == 0) out[(size_t)DD * NPIX + p] = (float)kwin;
        const float* wb = wT + (size_t)kwin * DD;
        float* op = out + (size_t)b * DD * HWW + hw;
        op[(size_t)lane * HWW]        = wb[lane];
        op[(size_t)(lane + 64) * HWW] = wb[lane + 64];
    }
}

extern "C" void kernel_launch(void* const* d_in, const int* in_sizes, int n_in,
                              void* d_out, int out_size, void* d_ws, size_t ws_size,
                              hipStream_t stream) {
    const float* x = (const float*)d_in[0];
    const float* w = (const float*)d_in[1];
    float* out = (float*)d_out;
    float* wsf = (float*)d_ws;

    float*  wT    = wsf + WS_WT;
    float*  e2    = wsf + WS_E2;
    int*    ctr   = (int*)(wsf + WS_CTR);
    int*    listA = (int*)(wsf + WS_LISTA);
    int*    listB = (int*)(wsf + WS_LISTB);
    short8* bhi   = (short8*)(wsf + WS_BHI);
    short8* blo   = (short8*)(wsf + WS_BLO);

    prep_wt   <<<dim3(128),  dim3(256), 0, stream>>>(w, wT);
    prep_bfrag<<<dim3(64),   dim3(256), 0, stream>>>(w, bhi, blo);
    prep_e2   <<<dim3(4),    dim3(256), 0, stream>>>(wT, e2, ctr);
    vq_screen <<<dim3(1024), dim3(256), 0, stream>>>(x, wT, e2, bhi, blo, out,
                                                     listA, listB, ctr);
    vq_pair   <<<dim3(256),  dim3(256), 0, stream>>>(x, wT, e2, listA, ctr);
    vq_full   <<<dim3(256),  dim3(256), 0, stream>>>(x, wT, e2, listB, ctr);
    vq_finish <<<dim3(256),  dim3(256), 0, stream>>>(wT, out, listA, listB, ctr);
}

// Round 6
// 453.649 us; speedup vs baseline: 2.9529x; 1.1442x over previous
//
#include <hip/hip_runtime.h>
#include <math.h>

#define DD   128
#define KK   1024
#define HWW  4096
#define NPIX 131072
#define EPS  1.5e-4f        // >= 3.8x the ~3.9e-5 worst-case pair-comparison bound
#define CAPA 32768
#define CAPB 8192

// ws layout in float slots:
#define WS_WT    0           // fp32 wT[K][D]            131072
#define WS_E2    131072      // fp32 e2[K]                 1024
#define WS_CTR   132096      // int ctrA, ctrB (pad 64)
#define WS_LISTA 132160      // int {p,k1,k2} x CAPA      98304
#define WS_LISTB 230464      // int {p} x CAPB            16384
#define WS_BHI   246848      // bf16 B-frags hi           65536
#define WS_BLO   312384      // bf16 B-frags lo           65536

typedef short  short8  __attribute__((ext_vector_type(8)));
typedef float  floatx4 __attribute__((ext_vector_type(4)));

static __device__ __forceinline__ unsigned short f2bf(float x) {
    unsigned u = __float_as_uint(x);
    return (unsigned short)((u + 0x7fffu + ((u >> 16) & 1u)) >> 16);
}
static __device__ __forceinline__ float bf2f(unsigned short b) {
    return __uint_as_float(((unsigned)b) << 16);
}

// ---------------------------------------------------------------------------
// Fused prep: [0,32768) transpose wT ; [32768,49152) bf16 hi/lo B-fragments
// (verified layout); [49152,50176) e2[k] numpy-order from w directly
// (identical FP sequence: acc = fadd(acc, fmul(v,v)) over d ascending).
// All phases read only w — no internal dependencies.
// ---------------------------------------------------------------------------
__global__ __launch_bounds__(256) void prep_all(
        const float* __restrict__ w,
        float* __restrict__ wT, float* __restrict__ e2,
        short8* __restrict__ bhi, short8* __restrict__ blo,
        int* __restrict__ ctr) {
    int t = blockIdx.x * 256 + threadIdx.x;
    if (t < 32768) {
        int k = t & 1023, d4 = t >> 10;
        float4 v;
        v.x = w[(d4 * 4 + 0) * KK + k];
        v.y = w[(d4 * 4 + 1) * KK + k];
        v.z = w[(d4 * 4 + 2) * KK + k];
        v.w = w[(d4 * 4 + 3) * KK + k];
        *(float4*)(wT + (size_t)k * DD + d4 * 4) = v;
    } else if (t < 49152) {
        int u     = t - 32768;
        int lane  = u & 63;
        int chunk = (u >> 6) & 3;
        int ktile = u >> 8;
        int kcol  = ktile * 16 + (lane & 15);
        int d0    = chunk * 32 + (lane >> 4) * 8;
        short8 h, l;
#pragma unroll
        for (int j = 0; j < 8; ++j) {
            float wv = w[(size_t)(d0 + j) * KK + kcol];
            unsigned short hb = f2bf(wv);
            h[j] = (short)hb;
            l[j] = (short)f2bf(wv - bf2f(hb));
        }
        bhi[u] = h;
        blo[u] = l;
    } else if (t < 50176) {
        int k = t - 49152;
        if (k == 0) { ctr[0] = 0; ctr[1] = 0; }
        float acc = 0.0f;
        for (int d = 0; d < DD; ++d) {
            float v = w[d * KK + k];
            acc = __fadd_rn(acc, __fmul_rn(v, v));
        }
        e2[k] = acc;
    }
}

// ---------------------------------------------------------------------------
// Screen: wave = 32 pixels x all 1024 k via split-bf16 MFMA (verified r5
// numerics). NEW: register double-buffer of the 8 fragment loads (prefetch
// kt+1 before the MFMA block) + cheaper min/max top-3 recurrence (same strict-<
// tie semantics). Classification -> listA (2-cand) / listB (3+-cand).
// ---------------------------------------------------------------------------
__global__ __launch_bounds__(256) void vq_screen(
        const float* __restrict__ x,
        const float* __restrict__ wT,
        const float* __restrict__ e2,
        const short8* __restrict__ bhi,
        const short8* __restrict__ blo,
        float* __restrict__ out,
        int* __restrict__ listA,
        int* __restrict__ listB,
        int* __restrict__ ctr) {
    __shared__ int sk1[4][32];

    const int tid  = threadIdx.x;
    const int wave = tid >> 6;
    const int lane = tid & 63;
    const int q    = lane >> 4;
    const int col  = lane & 15;

    const int b       = blockIdx.x >> 5;
    const int base_hw = (blockIdx.x & 31) * 128 + wave * 32;

    // A fragments: x[pixel][d = chunk*32 + q*8 + j], bf16 hi/lo split
    short8 a0h[4], a0l[4], a1h[4], a1l[4];
#pragma unroll
    for (int c = 0; c < 4; ++c) {
#pragma unroll
        for (int j = 0; j < 8; ++j) {
            int d = c * 32 + q * 8 + j;
            const float* xr = x + (size_t)(b * DD + d) * HWW + base_hw;
            float x0 = xr[col];
            float x1 = xr[16 + col];
            unsigned short h0 = f2bf(x0), h1 = f2bf(x1);
            a0h[c][j] = (short)h0;  a0l[c][j] = (short)f2bf(x0 - bf2f(h0));
            a1h[c][j] = (short)h1;  a1l[c][j] = (short)f2bf(x1 - bf2f(h1));
        }
    }

    float s1[8], s2[8], s3[8];
    int   c1[8], c2[8];
#pragma unroll
    for (int i = 0; i < 8; ++i) {
        s1[i] = INFINITY; s2[i] = INFINITY; s3[i] = INFINITY;
        c1[i] = 0; c2[i] = 0;
    }

    const short8* pbh = bhi + lane;
    const short8* pbl = blo + lane;
    // prefetch tile 0
    short8 nh0 = pbh[0],   nh1 = pbh[64],  nh2 = pbh[128], nh3 = pbh[192];
    short8 nl0 = pbl[0],   nl1 = pbl[64],  nl2 = pbl[128], nl3 = pbl[192];

    for (int kt = 0; kt < KK / 16; ++kt) {
        short8 bh0 = nh0, bh1 = nh1, bh2 = nh2, bh3 = nh3;
        short8 bl0 = nl0, bl1 = nl1, bl2 = nl2, bl3 = nl3;
        // issue next tile's loads before the MFMA block (wrap keeps in-bounds)
        const int nb = ((kt + 1) & 63) * 256;
        nh0 = pbh[nb];  nh1 = pbh[nb + 64];  nh2 = pbh[nb + 128];  nh3 = pbh[nb + 192];
        nl0 = pbl[nb];  nl1 = pbl[nb + 64];  nl2 = pbl[nb + 128];  nl3 = pbl[nb + 192];
        float e2v = e2[kt * 16 + col];

        floatx4 p00 = {0.f,0.f,0.f,0.f}, p01 = {0.f,0.f,0.f,0.f};
        floatx4 p10 = {0.f,0.f,0.f,0.f}, p11 = {0.f,0.f,0.f,0.f};
        p00 = __builtin_amdgcn_mfma_f32_16x16x32_bf16(a0h[0], bh0, p00, 0,0,0);
        p01 = __builtin_amdgcn_mfma_f32_16x16x32_bf16(a0h[1], bh1, p01, 0,0,0);
        p00 = __builtin_amdgcn_mfma_f32_16x16x32_bf16(a0h[2], bh2, p00, 0,0,0);
        p01 = __builtin_amdgcn_mfma_f32_16x16x32_bf16(a0h[3], bh3, p01, 0,0,0);
        p00 = __builtin_amdgcn_mfma_f32_16x16x32_bf16(a0h[0], bl0, p00, 0,0,0);
        p01 = __builtin_amdgcn_mfma_f32_16x16x32_bf16(a0h[1], bl1, p01, 0,0,0);
        p00 = __builtin_amdgcn_mfma_f32_16x16x32_bf16(a0h[2], bl2, p00, 0,0,0);
        p01 = __builtin_amdgcn_mfma_f32_16x16x32_bf16(a0h[3], bl3, p01, 0,0,0);
        p00 = __builtin_amdgcn_mfma_f32_16x16x32_bf16(a0l[0], bh0, p00, 0,0,0);
        p01 = __builtin_amdgcn_mfma_f32_16x16x32_bf16(a0l[1], bh1, p01, 0,0,0);
        p00 = __builtin_amdgcn_mfma_f32_16x16x32_bf16(a0l[2], bh2, p00, 0,0,0);
        p01 = __builtin_amdgcn_mfma_f32_16x16x32_bf16(a0l[3], bh3, p01, 0,0,0);
        p10 = __builtin_amdgcn_mfma_f32_16x16x32_bf16(a1h[0], bh0, p10, 0,0,0);
        p11 = __builtin_amdgcn_mfma_f32_16x16x32_bf16(a1h[1], bh1, p11, 0,0,0);
        p10 = __builtin_amdgcn_mfma_f32_16x16x32_bf16(a1h[2], bh2, p10, 0,0,0);
        p11 = __builtin_amdgcn_mfma_f32_16x16x32_bf16(a1h[3], bh3, p11, 0,0,0);
        p10 = __builtin_amdgcn_mfma_f32_16x16x32_bf16(a1h[0], bl0, p10, 0,0,0);
        p11 = __builtin_amdgcn_mfma_f32_16x16x32_bf16(a1h[1], bl1, p11, 0,0,0);
        p10 = __builtin_amdgcn_mfma_f32_16x16x32_bf16(a1h[2], bl2, p10, 0,0,0);
        p11 = __builtin_amdgcn_mfma_f32_16x16x32_bf16(a1h[3], bl3, p11, 0,0,0);
        p10 = __builtin_amdgcn_mfma_f32_16x16x32_bf16(a1l[0], bh0, p10, 0,0,0);
        p11 = __builtin_amdgcn_mfma_f32_16x16x32_bf16(a1l[1], bh1, p11, 0,0,0);
        p10 = __builtin_amdgcn_mfma_f32_16x16x32_bf16(a1l[2], bh2, p10, 0,0,0);
        p11 = __builtin_amdgcn_mfma_f32_16x16x32_bf16(a1l[3], bh3, p11, 0,0,0);

        const int kcur = kt * 16 + col;
#pragma unroll
        for (int g = 0; g < 2; ++g) {
#pragma unroll
            for (int r = 0; r < 4; ++r) {
                const int i = g * 4 + r;
                float s = fmaf(-2.0f,
                               (g == 0 ? p00[r] + p01[r] : p10[r] + p11[r]),
                               e2v);
                bool lt1 = s < s1[i];
                bool lt2 = s < s2[i];
                s3[i] = fminf(s3[i], fmaxf(s, s2[i]));   // uses s2_old
                s2[i] = fminf(s2[i], fmaxf(s, s1[i]));   // uses s1_old
                c2[i] = lt1 ? c1[i] : (lt2 ? kcur : c2[i]);
                s1[i] = fminf(s, s1[i]);
                c1[i] = lt1 ? kcur : c1[i];
            }
        }
    }

    // Butterfly merge of sorted top-3 states across the 16 k-columns (verified r5).
#pragma unroll
    for (int off = 1; off < 16; off <<= 1) {
#pragma unroll
        for (int i = 0; i < 8; ++i) {
            float o1 = __shfl_xor(s1[i], off);
            float o2 = __shfl_xor(s2[i], off);
            float o3 = __shfl_xor(s3[i], off);
            int   ok1 = __shfl_xor(c1[i], off);
            int   ok2 = __shfl_xor(c2[i], off);
            bool afirst = (s1[i] < o1) || (s1[i] == o1 && c1[i] < ok1);
            float n1, n2, n3; int nk1, nk2;
            if (afirst) {
                bool asec = (s2[i] < o1) || (s2[i] == o1 && c2[i] < ok1);
                n1 = s1[i]; nk1 = c1[i];
                n2 = asec ? s2[i] : o1;  nk2 = asec ? c2[i] : ok1;
                n3 = asec ? fminf(s3[i], o1) : fminf(s2[i], o2);
            } else {
                bool bsec = (o2 < s1[i]) || (o2 == s1[i] && ok2 < c1[i]);
                n1 = o1; nk1 = ok1;
                n2 = bsec ? o2 : s1[i];  nk2 = bsec ? ok2 : c1[i];
                n3 = bsec ? fminf(o3, s1[i]) : fminf(o2, s2[i]);
            }
            s1[i] = n1; s2[i] = n2; s3[i] = n3; c1[i] = nk1; c2[i] = nk2;
        }
    }

    // Publish (verified r5)
#pragma unroll
    for (int g = 0; g < 2; ++g) {
#pragma unroll
        for (int r = 0; r < 4; ++r) {
            if (col == r) {
                const int i = g * 4 + r;
                int plocal = g * 16 + q * 4 + r;
                int hwp    = base_hw + plocal;
                int Pg     = b * HWW + hwp;
                out[(size_t)DD * NPIX + Pg] = (float)c1[i];
                sk1[wave][plocal] = c1[i];
                float g12 = s2[i] - s1[i];
                float g13 = s3[i] - s1[i];
                if (g12 <= EPS) {
                    if (g13 > EPS) {
                        int idx = atomicAdd(&ctr[0], 1);
                        if (idx < CAPA) {
                            listA[3 * idx + 0] = Pg;
                            listA[3 * idx + 1] = c1[i];
                            listA[3 * idx + 2] = c2[i];
                        }
                    } else {
                        int idx = atomicAdd(&ctr[1], 1);
                        if (idx < CAPB) listB[idx] = Pg;
                    }
                }
            }
        }
    }
    __syncthreads();

    // Gather epilogue (verified r3-r5)
    {
        const int p_lo = lane & 15;
        const int dgrp = lane >> 4;
#pragma unroll
        for (int half = 0; half < 2; ++half) {
            const int plocal = half * 16 + p_lo;
            const int kk     = sk1[wave][plocal];
            const int hwp    = base_hw + plocal;
            const float* wrow = wT + (size_t)kk * DD;
#pragma unroll
            for (int i = 0; i < 32; ++i) {
                int d = i * 4 + dgrp;
                out[(size_t)(b * DD + d) * HWW + hwp] = wrow[d];
            }
        }
    }
}

// ---------------------------------------------------------------------------
// Fused resolve: (1) wave-per-entry full scans for listB (3+ candidates),
// (2) thread-per-entry exact pair resolve for listA. Each entry writes its
// own argmin + gathered row -> no finish kernel, no cross-block deps.
// All exact arithmetic byte-identical to the verified r5 kernels.
// ---------------------------------------------------------------------------
__global__ __launch_bounds__(256) void vq_resolve(
        const float* __restrict__ x,
        const float* __restrict__ wT,
        const float* __restrict__ e2,
        const int* __restrict__ listA,
        const int* __restrict__ listB,
        const int* __restrict__ ctr,
        float* __restrict__ out) {
    const int nA = min(ctr[0], CAPA);
    const int nB = min(ctr[1], CAPB);
    const int tid  = threadIdx.x;
    const int gtid = blockIdx.x * 256 + tid;
    const int wave = gtid >> 6;
    const int lane = tid & 63;
    const int NW = (gridDim.x * 256) >> 6;
    const int NT = gridDim.x * 256;

    // ---- full scans (rare) ----
    for (int j = wave; j < nB; j += NW) {
        const int p  = listB[j];
        const int b  = p >> 12;
        const int hw = p & (HWW - 1);
        const float* xp = x + (size_t)b * DD * HWW + hw;
        float xv[DD];
#pragma unroll 4
        for (int d = 0; d < DD; ++d) xv[d] = xp[(size_t)d * HWW];
        float x2 = 0.0f;
#pragma unroll 4
        for (int d = 0; d < DD; ++d) x2 = __fadd_rn(x2, __fmul_rn(xv[d], xv[d]));

        unsigned long long best = ~0ull;
        for (int kk = 0; kk < 16; ++kk) {
            const int k = lane * 16 + kk;
            const float* wk = wT + (size_t)k * DD;
            float a = 0.0f;
#pragma unroll 4
            for (int d = 0; d < DD; ++d)
                a = __fadd_rn(a, __fmul_rn(xv[d], wk[d]));
            float d2 = __fadd_rn(__fsub_rn(x2, 2.0f * a), e2[k]);
            unsigned long long c =
                ((unsigned long long)__float_as_uint(d2) << 32) | (unsigned)k;
            best = best < c ? best : c;
        }
#pragma unroll
        for (int off = 32; off; off >>= 1) {
            unsigned long long o = __shfl_xor(best, off);
            best = best < o ? best : o;
        }
        const int kwin = (int)(best & 0xffffffffu);
        if (lane == 0) out[(size_t)DD * NPIX + p] = (float)kwin;
        const float* wb = wT + (size_t)kwin * DD;
        float* op = out + (size_t)b * DD * HWW + hw;
        op[(size_t)lane * HWW]        = wb[lane];
        op[(size_t)(lane + 64) * HWW] = wb[lane + 64];
    }

    // ---- pair resolves (thread per entry, CU-spread mapping) ----
    for (int i = blockIdx.x + tid * gridDim.x; i < nA; i += NT) {
        const int p  = listA[3 * i + 0];
        const int kA = listA[3 * i + 1];
        const int kB = listA[3 * i + 2];
        const int b  = p >> 12;
        const int hw = p & (HWW - 1);
        const float* xp = x + (size_t)b * DD * HWW + hw;
        const float* wa = wT + (size_t)kA * DD;
        const float* wb = wT + (size_t)kB * DD;
        float x2 = 0.0f, aa = 0.0f, ab = 0.0f;
#pragma unroll 4
        for (int d = 0; d < DD; ++d) {
            float xd = xp[(size_t)d * HWW];
            x2 = __fadd_rn(x2, __fmul_rn(xd, xd));
            aa = __fadd_rn(aa, __fmul_rn(xd, wa[d]));
            ab = __fadd_rn(ab, __fmul_rn(xd, wb[d]));
        }
        float dA = __fadd_rn(__fsub_rn(x2, 2.0f * aa), e2[kA]);
        float dB = __fadd_rn(__fsub_rn(x2, 2.0f * ab), e2[kB]);
        const int kwin = (dA < dB || (dA == dB && kA < kB)) ? kA : kB;
        out[(size_t)DD * NPIX + p] = (float)kwin;
        const float* ww = wT + (size_t)kwin * DD;
        float* op = out + (size_t)b * DD * HWW + hw;
#pragma unroll 8
        for (int d = 0; d < DD; ++d) op[(size_t)d * HWW] = ww[d];
    }
}

extern "C" void kernel_launch(void* const* d_in, const int* in_sizes, int n_in,
                              void* d_out, int out_size, void* d_ws, size_t ws_size,
                              hipStream_t stream) {
    const float* x = (const float*)d_in[0];
    const float* w = (const float*)d_in[1];
    float* out = (float*)d_out;
    float* wsf = (float*)d_ws;

    float*  wT    = wsf + WS_WT;
    float*  e2    = wsf + WS_E2;
    int*    ctr   = (int*)(wsf + WS_CTR);
    int*    listA = (int*)(wsf + WS_LISTA);
    int*    listB = (int*)(wsf + WS_LISTB);
    short8* bhi   = (short8*)(wsf + WS_BHI);
    short8* blo   = (short8*)(wsf + WS_BLO);

    prep_all  <<<dim3(196),  dim3(256), 0, stream>>>(w, wT, e2, bhi, blo, ctr);
    vq_screen <<<dim3(1024), dim3(256), 0, stream>>>(x, wT, e2, bhi, blo, out,
                                                     listA, listB, ctr);
    vq_resolve<<<dim3(256),  dim3(256), 0, stream>>>(x, wT, e2, listA, listB,
                                                     ctr, out);
}